// Round 8
// baseline (61531.787 us; speedup 1.0000x reference)
//
#include <hip/hip_runtime.h>
#include <hip/hip_fp16.h>
#include <math.h>

#define NBLK 256
#define NTHR 1024

__device__ __forceinline__ float fast_rcp(float x) {
#if __has_builtin(__builtin_amdgcn_rcpf)
  return __builtin_amdgcn_rcpf(x);
#else
  return 1.f / x;
#endif
}
__device__ __forceinline__ float fast_sigmoid(float x) { return fast_rcp(1.f + __expf(-x)); }
__device__ __forceinline__ float fast_tanh(float x) { return 1.f - 2.f * fast_rcp(1.f + __expf(2.f * x)); }

union HU2 { unsigned int u; __half2 h; };
union HU4 { uint4 u; __half2 h[4]; };
__device__ __forceinline__ float2 cvt2(unsigned int u) { HU2 t; t.u = u; return __half22float2(t.h); }

__device__ __forceinline__ void sta(float* p, float v) {
  __hip_atomic_store(p, v, __ATOMIC_RELAXED, __HIP_MEMORY_SCOPE_AGENT);
}
__device__ __forceinline__ float lda(const float* p) {
  return __hip_atomic_load(p, __ATOMIC_RELAXED, __HIP_MEMORY_SCOPE_AGENT);
}
__device__ __forceinline__ int ldai(const int* p) {
  return __hip_atomic_load(p, __ATOMIC_RELAXED, __HIP_MEMORY_SCOPE_AGENT);
}

struct Params {
  const float *enc, *pre_w1, *pre_w2, *attn_bi, *attn_bh;
  const float *q_w, *k_w, *score_w, *score_b, *conv_w, *loc_w, *loc_b;
  const float *out_bi, *out_bh, *dec_b, *gate_b, *gate_w;
  const float *attn_wi, *attn_wh, *out_wi, *out_wh, *dec_w;
  const int *text_lens, *mel_lens;
  __half *hkeys, *gw1T, *gw2T, *decT, *pre1T, *pre2T, *locwh, *qwT;
  float *hA, *hO, *attw, *attcum, *ebuf, *zpart, *ctxacc, *stateZ;
  int *flagsA, *flagsB, *flagsC;
  float *out_mel, *out_gate, *out_attn, *out_mask;
};

// store own flag after all block stores drained (call after __syncthreads())
__device__ __forceinline__ void set_flag(int* f, int v, int tid) {
  if (tid == 0) {
    asm volatile("s_waitcnt vmcnt(0) lgkmcnt(0)" ::: "memory");
    __hip_atomic_store(f, v, __ATOMIC_RELAXED, __HIP_MEMORY_SCOPE_AGENT);
  }
}

// ---------------- prep: keys GEMM (fp16 out) ----------------
__global__ __launch_bounds__(512) void k_keys(Params p) {
  __shared__ float sA[16][132];
  __shared__ float sB[16][68];
  int tid = threadIdx.x;
  int row0 = blockIdx.x * 128, col0 = blockIdx.y * 64;
  float acc[4][4] = {};
  int r = tid >> 2, kq = tid & 3;
  int tx = tid & 15, ty = tid >> 4;
  for (int k0 = 0; k0 < 1024; k0 += 16) {
    __syncthreads();
    float4 a4 = *(const float4*)(p.enc + (size_t)(row0 + r) * 1024 + k0 + kq * 4);
    sA[kq * 4 + 0][r] = a4.x; sA[kq * 4 + 1][r] = a4.y;
    sA[kq * 4 + 2][r] = a4.z; sA[kq * 4 + 3][r] = a4.w;
    if (tid < 256) {
      int kb = tid >> 4, nb = (tid & 15) * 4;
      float4 b4 = *(const float4*)(p.k_w + (size_t)(k0 + kb) * 512 + col0 + nb);
      sB[kb][nb + 0] = b4.x; sB[kb][nb + 1] = b4.y;
      sB[kb][nb + 2] = b4.z; sB[kb][nb + 3] = b4.w;
    }
    __syncthreads();
#pragma unroll
    for (int k = 0; k < 16; k++) {
      float ar[4], br[4];
#pragma unroll
      for (int i = 0; i < 4; i++) { ar[i] = sA[k][ty * 4 + i]; br[i] = sB[k][tx * 4 + i]; }
#pragma unroll
      for (int i = 0; i < 4; i++)
#pragma unroll
        for (int j = 0; j < 4; j++) acc[i][j] = fmaf(ar[i], br[j], acc[i][j]);
    }
  }
#pragma unroll
  for (int i = 0; i < 4; i++)
#pragma unroll
    for (int j = 0; j < 4; j++)
      p.hkeys[(size_t)(row0 + ty * 4 + i) * 512 + col0 + tx * 4 + j] = __float2half(acc[i][j]);
}

// ---------------- prep: repack weights + zero state/flags ----------------
__global__ __launch_bounds__(256) void k_repack(Params p) {
  const int gsz = gridDim.x * 256;
  const int t0 = blockIdx.x * 256 + threadIdx.x;
  for (int i = t0; i < 1280 * 512; i += gsz) {
    int r = i >> 9, u = i & 511;
    const float* src = (r < 768) ? p.attn_wi + (size_t)r * 1536 : p.attn_wh + (size_t)(r - 768) * 1536;
    __half2* d = (__half2*)(p.gw1T + ((size_t)i << 2));
    d[0] = __halves2half2(__float2half(src[u]), __float2half(src[512 + u]));
    d[1] = __halves2half2(__float2half(src[1024 + u]), __float2half(0.f));
  }
  for (int i = t0; i < 1536 * 512; i += gsz) {
    int r = i >> 9, u = i & 511;
    const float* src = (r < 1024) ? p.out_wi + (size_t)r * 1536 : p.out_wh + (size_t)(r - 1024) * 1536;
    __half2* d = (__half2*)(p.gw2T + ((size_t)i << 2));
    d[0] = __halves2half2(__float2half(src[u]), __float2half(src[512 + u]));
    d[1] = __halves2half2(__float2half(src[1024 + u]), __float2half(0.f));
  }
  for (int i = t0; i < 512 * 512; i += gsz) {
    int k = i >> 9, a = i & 511;
    p.qwT[(size_t)a * 512 + k] = __float2half(p.q_w[(size_t)k * 512 + a]);
  }
  for (int i = t0; i < 1024 * 128; i += gsz) {
    int k = i >> 7, m = i & 127;
    p.decT[(size_t)m * 1024 + k] = __float2half(p.dec_w[(size_t)k * 128 + m]);
  }
  for (int i = t0; i < 16384; i += gsz) p.locwh[i] = __float2half(p.loc_w[i]);
  for (int i = t0; i < 128 * 256; i += gsz) {
    int m = i >> 8, pc = i & 255;
    p.pre1T[(size_t)pc * 128 + m] = __float2half(p.pre_w1[(size_t)m * 256 + pc]);
  }
  for (int i = t0; i < 256 * 256; i += gsz) {
    int k = i >> 8, pc = i & 255;
    p.pre2T[(size_t)pc * 256 + k] = __float2half(p.pre_w2[(size_t)k * 256 + pc]);
  }
  for (int i = t0; i < 98304; i += gsz) p.stateZ[i] = 0.f;   // hA,hO,attw,attcum
  for (int i = t0; i < 32768; i += gsz) p.ctxacc[i] = 0.f;
  for (int i = t0; i < 768; i += gsz) p.flagsA[i] = 0;       // A,B,C contiguous
  for (int i = t0; i < 12800; i += gsz) {
    int b = i / 400, t = i - b * 400;
    p.out_mask[i] = (t > p.mel_lens[b]) ? 1.f : 0.f;
  }
}

struct SMemMega {
  __half keysL[64 * 512];   // persistent P2 keys tile (64 KB)
  float ctxL[4][512];       // persistent ctx carry P3 -> next P1 (8 KB)
  float invZ[4];
  union {
    struct { float x[4][1536]; float4 part4[16][64];
             float xh[4][1024]; float red[1024]; float mel4[4][128]; float p1b[4][256]; } gr;
    struct { float locS[64][33]; float aw[94]; float ac[94]; float hA_s[512]; float qS[512];
             float qpart[2][512]; float cpred[8][512]; float eS[64]; } s3;
  } u;
};

// GRU compute: x staged in sm.u.gr.x; block owns 16 u's (uG = ug*16+u), 4 batches
template <int DXI, int RPK>
__device__ __forceinline__ void gru_compute(SMemMega& sm, const uint2* w512,
    const float* __restrict__ bi, const float* __restrict__ bh,
    float* __restrict__ hnext, int ug, int b0, int tid) {
  const int u = tid & 15, b2 = (tid >> 4) & 3, ks = tid >> 6;
  const int uG = (ug << 4) + u;
  float ar = 0.f, az = 0.f, ani = 0.f, anh = 0.f;
  const uint2* w = w512 + (size_t)(ks * RPK) * 512 + uG;
#pragma unroll 8
  for (int j = 0; j < RPK; j++) {
    uint2 wv = w[(size_t)j * 512];
    int r = ks * RPK + j;
    float x = sm.u.gr.x[b2][r];
    float2 f0 = cvt2(wv.x);
    float2 f1 = cvt2(wv.y);
    ar = fmaf(x, f0.x, ar);
    az = fmaf(x, f0.y, az);
    float t = x * f1.x;
    if (r < DXI) ani += t; else anh += t;
  }
  sm.u.gr.part4[ks][(u << 2) + b2] = make_float4(ar, az, ani, anh);
  __syncthreads();
  if (tid < 64) {
    int uu = tid >> 2, bb2 = tid & 3;
    float4 s = make_float4(0.f, 0.f, 0.f, 0.f);
#pragma unroll
    for (int l = 0; l < 16; l++) {
      float4 v = sm.u.gr.part4[l][(uu << 2) + bb2];
      s.x += v.x; s.y += v.y; s.z += v.z; s.w += v.w;
    }
    int uGf = (ug << 4) + uu;
    float r = fast_sigmoid(s.x + bi[uGf] + bh[uGf]);
    float z = fast_sigmoid(s.y + bi[512 + uGf] + bh[512 + uGf]);
    float n = fast_tanh(s.z + bi[1024 + uGf] + r * (s.w + bh[1024 + uGf]));
    float hv = sm.u.gr.x[bb2][DXI + uGf];
    sta(&hnext[((size_t)(b0 + bb2) << 9) + uGf], (1.f - z) * n + z * hv);
  }
}

__global__ __launch_bounds__(NTHR) void mega(Params p) {
  __shared__ SMemMega sm;
  const int blk = blockIdx.x, tid = threadIdx.x;
  const int ug = blk & 31, bg = blk >> 5, b0 = bg * 4;  // P1/P3 identity
  const int bS = blk & 31, t8 = blk >> 5, t0g = t8 << 6; // P2 identity

  // one-time: keys tile -> LDS, zero ctxL
  {
    const uint4* src = (const uint4*)(p.hkeys + (((size_t)(bS << 9) + t0g) << 9));
    uint4* dst = (uint4*)sm.keysL;
    for (int i = tid; i < 4096; i += NTHR) dst[i] = src[i];
    for (int i = tid; i < 2048; i += NTHR) sm.ctxL[i >> 9][i & 511] = 0.f;
  }
  __syncthreads();

#pragma clang loop unroll(disable)
  for (int step = 0; step <= 400; step++) {
    const int par = step & 1;
    float* hA_prev = p.hA + par * 16384;
    float* hA_next = p.hA + (par ^ 1) * 16384;
    float* hO_prev = p.hO + par * 16384;
    float* hO_next = p.hO + (par ^ 1) * 16384;

    // ======== P1: wait prev-step P3, prenet(mel) local, GRU1 ========
    if (tid < 64) {
      const int* f = p.flagsC + (bg << 5);
      while (true) {
        int v = (tid < 32) ? ldai(&f[tid]) : 0x7fffffff;
        if (__all(v >= step)) break;
        __builtin_amdgcn_s_sleep(1);
      }
    }
    __syncthreads();
    if (ug == 0) {
      for (int i = tid; i < 2048; i += NTHR)
        sta(&p.ctxacc[((par ^ 1) << 14) + (b0 << 9) + i], 0.f);
    }
    // stage xh = [hO_prev | ctxL], and x's ctx/hA slots
    for (int i = tid; i < 4096; i += NTHR) {
      int b2 = i >> 10, r = i & 1023;
      sm.u.gr.xh[b2][r] = (r < 512) ? lda(&hO_prev[((size_t)(b0 + b2) << 9) + r])
                                    : sm.ctxL[b2][r - 512];
    }
    if (step < 400) {
      for (int i = tid; i < 2048; i += NTHR) {
        int b2 = i >> 9, a = i & 511;
        sm.u.gr.x[b2][256 + a] = sm.ctxL[b2][a];
      }
      for (int i = tid; i < 2048; i += NTHR) {
        int b2 = i >> 9, a = i & 511;
        sm.u.gr.x[b2][768 + a] = lda(&hA_prev[((size_t)(b0 + b2) << 9) + a]);
      }
    }
    __syncthreads();
    // mel partials: (m, b2, ks)
    {
      int m = tid & 127, b2 = (tid >> 7) & 3, ks = tid >> 9;
      const HU4* dp = (const HU4*)(p.decT + (size_t)m * 1024 + ks * 512);
      float a = 0.f;
#pragma unroll 4
      for (int it = 0; it < 64; it++) {
        HU4 raw = dp[it];
        int kb = ks * 512 + it * 8;
#pragma unroll
        for (int h2 = 0; h2 < 4; h2++) {
          float2 w = __half22float2(raw.h[h2]);
          a = fmaf(sm.u.gr.xh[b2][kb + h2 * 2], w.x, a);
          a = fmaf(sm.u.gr.xh[b2][kb + h2 * 2 + 1], w.y, a);
        }
      }
      sm.u.gr.red[tid] = a;
    }
    __syncthreads();
    if (tid < 512) {
      int m = tid & 127, b2 = tid >> 7;
      float mv = sm.u.gr.red[tid] + sm.u.gr.red[tid + 512] + p.dec_b[m];
      sm.u.gr.mel4[b2][m] = mv;
      if (ug == 0 && step >= 1) {
        int bb = b0 + b2;
        bool masked = (step - 1) > p.mel_lens[bb];
        p.out_mel[(size_t)bb * 51200 + (size_t)(step - 1) * 128 + m] = masked ? 0.f : mv;
      }
    }
    if (ug == 0 && step >= 1 && tid < 256) {
      int b2 = tid >> 6, lane = tid & 63;
      float g = 0.f;
#pragma unroll
      for (int j = 0; j < 16; j++) {
        int k = lane + (j << 6);
        g = fmaf(sm.u.gr.xh[b2][k], p.gate_w[k], g);
      }
#pragma unroll
      for (int off = 32; off > 0; off >>= 1) g += __shfl_xor(g, off, 64);
      if (lane == 0) {
        int bb = b0 + b2;
        bool masked = (step - 1) > p.mel_lens[bb];
        p.out_gate[bb * 400 + (step - 1)] = masked ? 1000.f : (g + p.gate_b[0]);
      }
    }
    if (step == 400) return;
    __syncthreads();
    // prenet1
    {
      int pc = tid & 255, b2 = tid >> 8;
      const HU4* wp = (const HU4*)(p.pre1T + (size_t)pc * 128);
      float a = 0.f;
#pragma unroll 4
      for (int it = 0; it < 16; it++) {
        HU4 raw = wp[it];
        int kb = it * 8;
#pragma unroll
        for (int h2 = 0; h2 < 4; h2++) {
          float2 w = __half22float2(raw.h[h2]);
          a = fmaf(sm.u.gr.mel4[b2][kb + h2 * 2], w.x, a);
          a = fmaf(sm.u.gr.mel4[b2][kb + h2 * 2 + 1], w.y, a);
        }
      }
      __syncthreads();
      sm.u.gr.p1b[b2][pc] = fmaxf(a, 0.f);
    }
    __syncthreads();
    // prenet2 -> decin slot of x
    {
      int pc = tid & 255, b2 = tid >> 8;
      const HU4* wp = (const HU4*)(p.pre2T + (size_t)pc * 256);
      float a = 0.f;
#pragma unroll 4
      for (int it = 0; it < 32; it++) {
        HU4 raw = wp[it];
        int kb = it * 8;
#pragma unroll
        for (int h2 = 0; h2 < 4; h2++) {
          float2 w = __half22float2(raw.h[h2]);
          a = fmaf(sm.u.gr.p1b[b2][kb + h2 * 2], w.x, a);
          a = fmaf(sm.u.gr.p1b[b2][kb + h2 * 2 + 1], w.y, a);
        }
      }
      sm.u.gr.x[b2][pc] = (step == 0) ? 0.f : fmaxf(a, 0.f);
    }
    __syncthreads();
    gru_compute<768, 80>(sm, (const uint2*)p.gw1T, p.attn_bi, p.attn_bh,
                         hA_next, ug, b0, tid);
    __syncthreads();
    set_flag(&p.flagsA[blk], step + 1, tid);

    // ======== P2: conv + q + score + e + ctx-partial atomics ========
    if (tid < 64) {
      const int* f = p.flagsA + ((bS >> 2) << 5);
      while (true) {
        int v = (tid < 32) ? ldai(&f[tid]) : 0x7fffffff;
        if (__all(v >= step + 1)) break;
        __builtin_amdgcn_s_sleep(1);
      }
    }
    __syncthreads();
    {
      const int tlen = p.text_lens[bS];
      for (int j = tid; j < 94; j += NTHR) {
        int pp = t0g - 15 + j;
        bool ok = (unsigned)pp < 512u;
        sm.u.s3.aw[j] = ok ? lda(&p.attw[(bS << 9) + pp]) : 0.f;
        sm.u.s3.ac[j] = ok ? lda(&p.attcum[(bS << 9) + pp]) : 0.f;
      }
      if (tid < 512) sm.u.s3.hA_s[tid] = lda(&hA_next[(bS << 9) + tid]);
      __syncthreads();
      for (int i = tid; i < 2048; i += NTHR) {
        int tt = i >> 5, f = i & 31;
        const float* w0 = p.conv_w + f * 62;
        float a = 0.f;
#pragma unroll
        for (int k = 0; k < 31; k++)
          a = fmaf(w0[k], sm.u.s3.aw[tt + k], fmaf(w0[31 + k], sm.u.s3.ac[tt + k], a));
        sm.u.s3.locS[tt][f] = a;
      }
      {
        int a = tid & 511, ks = tid >> 9;
        const HU4* qp = (const HU4*)(p.qwT + (size_t)a * 512 + ks * 256);
        float q0 = 0.f, q1 = 0.f;
#pragma unroll 4
        for (int it = 0; it < 32; it++) {
          HU4 raw = qp[it];
          int kb = ks * 256 + it * 8;
#pragma unroll
          for (int h2 = 0; h2 < 4; h2++) {
            float2 w = __half22float2(raw.h[h2]);
            q0 = fmaf(sm.u.s3.hA_s[kb + h2 * 2], w.x, q0);
            q1 = fmaf(sm.u.s3.hA_s[kb + h2 * 2 + 1], w.y, q1);
          }
        }
        sm.u.s3.qpart[ks][a] = q0 + q1;
      }
      __syncthreads();
      if (tid < 512)
        sm.u.s3.qS[tid] = sm.u.s3.qpart[0][tid] + sm.u.s3.qpart[1][tid] + p.loc_b[tid];
      __syncthreads();
      const int lane = tid & 63, wv = tid >> 6;
      float acc[4][8];
      float4 qA = *(const float4*)&sm.u.s3.qS[lane * 8];
      float4 qB = *(const float4*)&sm.u.s3.qS[lane * 8 + 4];
#pragma unroll
      for (int j = 0; j < 4; j++) {
        int tL = wv * 4 + j;
        HU4 raw; raw.u = *(const uint4*)&sm.keysL[tL * 512 + lane * 8];
        float2 k0 = __half22float2(raw.h[0]), k1 = __half22float2(raw.h[1]);
        float2 k2 = __half22float2(raw.h[2]), k3 = __half22float2(raw.h[3]);
        acc[j][0] = qA.x + k0.x; acc[j][1] = qA.y + k0.y;
        acc[j][2] = qA.z + k1.x; acc[j][3] = qA.w + k1.y;
        acc[j][4] = qB.x + k2.x; acc[j][5] = qB.y + k2.y;
        acc[j][6] = qB.z + k3.x; acc[j][7] = qB.w + k3.y;
      }
#pragma unroll 4
      for (int f = 0; f < 32; f++) {
        HU4 rw; rw.u = *(const uint4*)(p.locwh + (size_t)f * 512 + lane * 8);
        float2 w0 = __half22float2(rw.h[0]), w1 = __half22float2(rw.h[1]);
        float2 w2 = __half22float2(rw.h[2]), w3 = __half22float2(rw.h[3]);
#pragma unroll
        for (int j = 0; j < 4; j++) {
          float lf = sm.u.s3.locS[wv * 4 + j][f];
          acc[j][0] = fmaf(lf, w0.x, acc[j][0]); acc[j][1] = fmaf(lf, w0.y, acc[j][1]);
          acc[j][2] = fmaf(lf, w1.x, acc[j][2]); acc[j][3] = fmaf(lf, w1.y, acc[j][3]);
          acc[j][4] = fmaf(lf, w2.x, acc[j][4]); acc[j][5] = fmaf(lf, w2.y, acc[j][5]);
          acc[j][6] = fmaf(lf, w3.x, acc[j][6]); acc[j][7] = fmaf(lf, w3.y, acc[j][7]);
        }
      }
      float4 sA = *(const float4*)(p.score_w + lane * 8);
      float4 sB = *(const float4*)(p.score_w + lane * 8 + 4);
      float sbias = p.score_b[0];
      float e_reg[4];
#pragma unroll
      for (int j = 0; j < 4; j++) {
        float pv = fast_tanh(acc[j][0]) * sA.x + fast_tanh(acc[j][1]) * sA.y +
                   fast_tanh(acc[j][2]) * sA.z + fast_tanh(acc[j][3]) * sA.w +
                   fast_tanh(acc[j][4]) * sB.x + fast_tanh(acc[j][5]) * sB.y +
                   fast_tanh(acc[j][6]) * sB.z + fast_tanh(acc[j][7]) * sB.w;
#pragma unroll
        for (int off = 32; off > 0; off >>= 1) pv += __shfl_xor(pv, off, 64);
        int t = t0g + wv * 4 + j;
        e_reg[j] = (t > tlen) ? 0.f : __expf(pv + sbias);
      }
      if (lane == 0) {
#pragma unroll
        for (int j = 0; j < 4; j++) sm.u.s3.eS[wv * 4 + j] = e_reg[j];
      }
      float cp[8] = {0.f, 0.f, 0.f, 0.f, 0.f, 0.f, 0.f, 0.f};
#pragma unroll
      for (int j = 0; j < 4; j++) {
        int tL = wv * 4 + j;
        HU4 raw; raw.u = *(const uint4*)&sm.keysL[tL * 512 + lane * 8];
        float2 k0 = __half22float2(raw.h[0]), k1 = __half22float2(raw.h[1]);
        float2 k2 = __half22float2(raw.h[2]), k3 = __half22float2(raw.h[3]);
        float e = e_reg[j];
        cp[0] = fmaf(e, k0.x, cp[0]); cp[1] = fmaf(e, k0.y, cp[1]);
        cp[2] = fmaf(e, k1.x, cp[2]); cp[3] = fmaf(e, k1.y, cp[3]);
        cp[4] = fmaf(e, k2.x, cp[4]); cp[5] = fmaf(e, k2.y, cp[5]);
        cp[6] = fmaf(e, k3.x, cp[6]); cp[7] = fmaf(e, k3.y, cp[7]);
      }
      __syncthreads();
      if (wv < 8) {
        float4* r0 = (float4*)&sm.u.s3.cpred[wv][lane * 8];
        r0[0] = make_float4(cp[0], cp[1], cp[2], cp[3]);
        r0[1] = make_float4(cp[4], cp[5], cp[6], cp[7]);
      }
      __syncthreads();
      if (wv >= 8) {
        float* r0 = &sm.u.s3.cpred[wv - 8][lane * 8];
#pragma unroll
        for (int i = 0; i < 8; i++) r0[i] += cp[i];
      }
      __syncthreads();
      if (tid < 512) {
        float s = 0.f;
#pragma unroll
        for (int j = 0; j < 8; j++) s += sm.u.s3.cpred[j][tid];
        atomicAdd(&p.ctxacc[(par << 14) + (bS << 9) + tid], s);
      }
      if (tid < 64) {
        float e = sm.u.s3.eS[tid];
        sta(&p.ebuf[(bS << 9) + t0g + tid], e);
        float z = e;
#pragma unroll
        for (int off = 32; off > 0; off >>= 1) z += __shfl_xor(z, off, 64);
        if (tid == 0) sta(&p.zpart[bS * 8 + t8], z);
      }
    }
    __syncthreads();
    set_flag(&p.flagsB[blk], step + 1, tid);

    // ======== P3: ctx normalize + GRU2 ========
    if (tid < 64) {
      while (true) {
        int v = 0x7fffffff;
        if (tid < 32) {
          int tt8 = tid >> 2, b = b0 + (tid & 3);
          v = ldai(&p.flagsB[(tt8 << 5) + b]);
        }
        if (__all(v >= step + 1)) break;
        __builtin_amdgcn_s_sleep(1);
      }
    }
    __syncthreads();
    {
      if (tid < 4) {
        float Z = 0.f;
#pragma unroll
        for (int j = 0; j < 8; j++) Z += lda(&p.zpart[(b0 + tid) * 8 + j]);
        sm.invZ[tid] = fast_rcp(Z);
      }
      __syncthreads();
      for (int i = tid; i < 2048; i += NTHR) {
        int b2 = i >> 9, a = i & 511;
        sm.ctxL[b2][a] = lda(&p.ctxacc[(par << 14) + ((b0 + b2) << 9) + a]) * sm.invZ[b2];
      }
      if (ug == 0) {
        for (int i = tid; i < 2048; i += NTHR) {
          int b2 = i >> 9, t = i & 511;
          int bb = b0 + b2;
          float v = lda(&p.ebuf[(bb << 9) + t]) * sm.invZ[b2];
          sta(&p.attw[(bb << 9) + t], v);
          float oc = lda(&p.attcum[(bb << 9) + t]);
          sta(&p.attcum[(bb << 9) + t], oc + v);
          p.out_attn[(size_t)bb * 204800 + (size_t)step * 512 + t] = v;
        }
      }
      // GRU2 staging: [hA_next | ctxL | hO_prev]
      for (int i = tid; i < 2048; i += NTHR) {
        int b2 = i >> 9, a = i & 511;
        sm.u.gr.x[b2][a] = lda(&hA_next[((size_t)(b0 + b2) << 9) + a]);
      }
      __syncthreads();
      for (int i = tid; i < 2048; i += NTHR) {
        int b2 = i >> 9, a = i & 511;
        sm.u.gr.x[b2][512 + a] = sm.ctxL[b2][a];
      }
      for (int i = tid; i < 2048; i += NTHR) {
        int b2 = i >> 9, a = i & 511;
        sm.u.gr.x[b2][1024 + a] = lda(&hO_prev[((size_t)(b0 + b2) << 9) + a]);
      }
      __syncthreads();
      gru_compute<1024, 96>(sm, (const uint2*)p.gw2T, p.out_bi, p.out_bh,
                            hO_next, ug, b0, tid);
    }
    __syncthreads();
    set_flag(&p.flagsC[blk], step + 1, tid);
  }
}

extern "C" void kernel_launch(void* const* d_in, const int* in_sizes, int n_in,
                              void* d_out, int out_size, void* d_ws, size_t ws_size,
                              hipStream_t stream) {
  Params p;
  p.enc       = (const float*)d_in[0];
  p.text_lens = (const int*)d_in[2];
  p.mel_lens  = (const int*)d_in[3];
  p.pre_w1    = (const float*)d_in[5];
  p.pre_w2    = (const float*)d_in[6];
  p.attn_wi   = (const float*)d_in[7];
  p.attn_wh   = (const float*)d_in[8];
  p.attn_bi   = (const float*)d_in[9];
  p.attn_bh   = (const float*)d_in[10];
  p.q_w       = (const float*)d_in[11];
  p.k_w       = (const float*)d_in[12];
  p.score_w   = (const float*)d_in[13];
  p.score_b   = (const float*)d_in[14];
  p.conv_w    = (const float*)d_in[15];
  p.loc_w     = (const float*)d_in[16];
  p.loc_b     = (const float*)d_in[17];
  p.out_wi    = (const float*)d_in[18];
  p.out_wh    = (const float*)d_in[19];
  p.out_bi    = (const float*)d_in[20];
  p.out_bh    = (const float*)d_in[21];
  p.dec_w     = (const float*)d_in[22];
  p.dec_b     = (const float*)d_in[23];
  p.gate_w    = (const float*)d_in[24];
  p.gate_b    = (const float*)d_in[25];

  float* ws = (float*)d_ws;
  p.hkeys  = (__half*)(ws);                    // 8,388,608 halfs
  p.gw1T   = (__half*)(ws + 4194304);          // 2,621,440 halfs
  p.gw2T   = (__half*)(ws + 5505024);          // 3,145,728 halfs
  p.decT   = (__half*)(ws + 7077888);          // 131,072 halfs
  p.pre1T  = (__half*)(ws + 7143424);          // 32,768
  p.pre2T  = (__half*)(ws + 7159808);          // 65,536
  p.locwh  = (__half*)(ws + 7192576);          // 16,384
  p.qwT    = (__half*)(ws + 7200768);          // 262,144
  p.hA     = ws + 7331840;                     // 2 x 16384
  p.hO     = ws + 7364608;                     // 2 x 16384
  p.attw   = ws + 7397376;                     // 16384
  p.attcum = ws + 7413760;                     // 16384
  p.stateZ = p.hA;                             // zero region: hA,hO,attw,attcum = 98,304
  p.ebuf   = ws + 7430144;                     // 16384
  p.zpart  = ws + 7446528;                     // 256
  p.ctxacc = ws + 7446784;                     // 2 x 16384
  p.flagsA = (int*)(ws + 7479552);             // 256
  p.flagsB = p.flagsA + 256;                   // 256
  p.flagsC = p.flagsA + 512;                   // 256
  float* out = (float*)d_out;
  p.out_mel  = out;
  p.out_gate = out + 1638400;
  p.out_attn = out + 1651200;
  p.out_mask = out + 8204800;

  k_repack<<<2048, 256, 0, stream>>>(p);
  k_keys<<<dim3(128, 8), 512, 0, stream>>>(p);
  void* args[] = { (void*)&p };
  hipLaunchCooperativeKernel((const void*)mega, dim3(NBLK), dim3(NTHR), args, 0, stream);
}

// Round 9
// 42520.984 us; speedup vs baseline: 1.4471x; 1.4471x over previous
//
#include <hip/hip_runtime.h>
#include <hip/hip_fp16.h>
#include <math.h>

#define NBLK 256
#define NTHR 1024

__device__ __forceinline__ float fast_rcp(float x) {
#if __has_builtin(__builtin_amdgcn_rcpf)
  return __builtin_amdgcn_rcpf(x);
#else
  return 1.f / x;
#endif
}
__device__ __forceinline__ float fast_sigmoid(float x) { return fast_rcp(1.f + __expf(-x)); }
__device__ __forceinline__ float fast_tanh(float x) { return 1.f - 2.f * fast_rcp(1.f + __expf(2.f * x)); }

union HU2 { unsigned int u; __half2 h; };
union HU4 { uint4 u; __half2 h[4]; };
__device__ __forceinline__ float2 cvt2(unsigned int u) { HU2 t; t.u = u; return __half22float2(t.h); }

__device__ __forceinline__ void sta(float* p, float v) {
  __hip_atomic_store(p, v, __ATOMIC_RELAXED, __HIP_MEMORY_SCOPE_AGENT);
}
__device__ __forceinline__ float lda(const float* p) {
  return __hip_atomic_load(p, __ATOMIC_RELAXED, __HIP_MEMORY_SCOPE_AGENT);
}
__device__ __forceinline__ int ldai(const int* p) {
  return __hip_atomic_load(p, __ATOMIC_RELAXED, __HIP_MEMORY_SCOPE_AGENT);
}

struct Params {
  const float *enc, *pre_w1, *pre_w2, *attn_bi, *attn_bh;
  const float *q_w, *k_w, *score_w, *score_b, *conv_w, *loc_w, *loc_b;
  const float *out_bi, *out_bh, *dec_b, *gate_b;
  const float *attn_wi, *attn_wh, *out_wi, *out_wh, *dec_w, *gate_w;
  const int *text_lens, *mel_lens;
  __half *hkeys, *gw1T, *gw2T, *decT, *pre1T, *pre2T, *gateh, *locwh, *qwT;
  float *hA, *hO, *attw, *attcum, *decin, *ebuf, *zpart, *ctxacc, *stateZ;
  int *flagsA, *flagsD;
  unsigned *barc;
  float *out_mel, *out_gate, *out_attn, *out_mask;
};

// two-level flag barrier (no L2 writeback/invalidate)
__device__ __forceinline__ void gbar(unsigned* flags, unsigned* gen, unsigned e,
                                     int blk, int tid) {
  __syncthreads();
  if (tid == 0) {
    asm volatile("s_waitcnt vmcnt(0) lgkmcnt(0)" ::: "memory");
    __hip_atomic_store(&flags[blk], e, __ATOMIC_RELAXED, __HIP_MEMORY_SCOPE_AGENT);
  }
  if (blk == 0) {
    if (tid < 64) {
      while (true) {
        bool ok = true;
#pragma unroll
        for (int j = 0; j < 4; j++) {
          unsigned v = __hip_atomic_load(&flags[tid * 4 + j], __ATOMIC_RELAXED,
                                         __HIP_MEMORY_SCOPE_AGENT);
          ok &= (v >= e);
        }
        if (__all(ok)) break;
        __builtin_amdgcn_s_sleep(1);
      }
      if (tid == 0)
        __hip_atomic_store(gen, e, __ATOMIC_RELAXED, __HIP_MEMORY_SCOPE_AGENT);
    }
  } else {
    if (tid == 0) {
      while (__hip_atomic_load(gen, __ATOMIC_RELAXED, __HIP_MEMORY_SCOPE_AGENT) < e)
        __builtin_amdgcn_s_sleep(2);
    }
  }
  asm volatile("" ::: "memory");
  __syncthreads();
}

// ---------------- prep: keys GEMM (fp16 out) ----------------
__global__ __launch_bounds__(512) void k_keys(Params p) {
  __shared__ float sA[16][132];
  __shared__ float sB[16][68];
  int tid = threadIdx.x;
  int row0 = blockIdx.x * 128, col0 = blockIdx.y * 64;
  float acc[4][4] = {};
  int r = tid >> 2, kq = tid & 3;
  int tx = tid & 15, ty = tid >> 4;
  for (int k0 = 0; k0 < 1024; k0 += 16) {
    __syncthreads();
    float4 a4 = *(const float4*)(p.enc + (size_t)(row0 + r) * 1024 + k0 + kq * 4);
    sA[kq * 4 + 0][r] = a4.x; sA[kq * 4 + 1][r] = a4.y;
    sA[kq * 4 + 2][r] = a4.z; sA[kq * 4 + 3][r] = a4.w;
    if (tid < 256) {
      int kb = tid >> 4, nb = (tid & 15) * 4;
      float4 b4 = *(const float4*)(p.k_w + (size_t)(k0 + kb) * 512 + col0 + nb);
      sB[kb][nb + 0] = b4.x; sB[kb][nb + 1] = b4.y;
      sB[kb][nb + 2] = b4.z; sB[kb][nb + 3] = b4.w;
    }
    __syncthreads();
#pragma unroll
    for (int k = 0; k < 16; k++) {
      float ar[4], br[4];
#pragma unroll
      for (int i = 0; i < 4; i++) { ar[i] = sA[k][ty * 4 + i]; br[i] = sB[k][tx * 4 + i]; }
#pragma unroll
      for (int i = 0; i < 4; i++)
#pragma unroll
        for (int j = 0; j < 4; j++) acc[i][j] = fmaf(ar[i], br[j], acc[i][j]);
    }
  }
#pragma unroll
  for (int i = 0; i < 4; i++)
#pragma unroll
    for (int j = 0; j < 4; j++)
      p.hkeys[(size_t)(row0 + ty * 4 + i) * 512 + col0 + tx * 4 + j] = __float2half(acc[i][j]);
}

// ---------------- prep: repack weights + zero state/flags ----------------
__global__ __launch_bounds__(256) void k_repack(Params p) {
  const int gsz = gridDim.x * 256;
  const int t0 = blockIdx.x * 256 + threadIdx.x;
  for (int i = t0; i < 1280 * 512; i += gsz) {
    int r = i >> 9, u = i & 511;
    const float* src = (r < 768) ? p.attn_wi + (size_t)r * 1536 : p.attn_wh + (size_t)(r - 768) * 1536;
    __half2* d = (__half2*)(p.gw1T + ((size_t)i << 2));
    d[0] = __halves2half2(__float2half(src[u]), __float2half(src[512 + u]));
    d[1] = __halves2half2(__float2half(src[1024 + u]), __float2half(0.f));
  }
  for (int i = t0; i < 1536 * 512; i += gsz) {
    int r = i >> 9, u = i & 511;
    const float* src = (r < 1024) ? p.out_wi + (size_t)r * 1536 : p.out_wh + (size_t)(r - 1024) * 1536;
    __half2* d = (__half2*)(p.gw2T + ((size_t)i << 2));
    d[0] = __halves2half2(__float2half(src[u]), __float2half(src[512 + u]));
    d[1] = __halves2half2(__float2half(src[1024 + u]), __float2half(0.f));
  }
  for (int i = t0; i < 512 * 512; i += gsz) {
    int k = i >> 9, a = i & 511;
    p.qwT[(size_t)a * 512 + k] = __float2half(p.q_w[(size_t)k * 512 + a]);
  }
  for (int i = t0; i < 1024 * 128; i += gsz) {
    int k = i >> 7, m = i & 127;
    p.decT[(size_t)m * 1024 + k] = __float2half(p.dec_w[(size_t)k * 128 + m]);
  }
  for (int i = t0; i < 1024; i += gsz) p.gateh[i] = __float2half(p.gate_w[i]);
  for (int i = t0; i < 16384; i += gsz) p.locwh[i] = __float2half(p.loc_w[i]);
  for (int i = t0; i < 128 * 256; i += gsz) {
    int m = i >> 8, pc = i & 255;
    p.pre1T[(size_t)pc * 128 + m] = __float2half(p.pre_w1[(size_t)m * 256 + pc]);
  }
  for (int i = t0; i < 256 * 256; i += gsz) {
    int k = i >> 8, pc = i & 255;
    p.pre2T[(size_t)pc * 256 + k] = __float2half(p.pre_w2[(size_t)k * 256 + pc]);
  }
  for (int i = t0; i < 106496; i += gsz) p.stateZ[i] = 0.f;  // hA,hO,attw,attcum,decin
  for (int i = t0; i < 16384; i += gsz) p.ctxacc[i] = 0.f;
  for (int i = t0; i < 288; i += gsz) p.flagsA[i] = 0;       // flagsA[256]+flagsD[32]
  for (int i = t0; i < 512; i += gsz) p.barc[i] = 0u;
  for (int i = t0; i < 12800; i += gsz) {
    int b = i / 400, t = i - b * 400;
    p.out_mask[i] = (t > p.mel_lens[b]) ? 1.f : 0.f;
  }
}

struct SMemMega {
  __half keysL[64 * 512];   // persistent P2 keys tile (64 KB)
  float ctxL[4][512];       // persistent ctx carry P3 -> next P1 (8 KB)
  float invZ[4];
  union {
    struct { float x[4][1536]; float4 part4[16][64]; } gr;
    struct { float locS[64][33]; float aw[94]; float ac[94]; float hA_s[512]; float qS[512];
             float qpart[2][512]; float cpred[8][512]; float eS[64]; } s3;
    struct { float xh[1024]; float red[1024]; float mel[128]; float p1[256]; } s6;
  } u;
};

// GRU compute: x staged in sm.u.gr.x; block owns 16 u's (uG = ug*16+u), 4 batches
template <int DXI, int RPK>
__device__ __forceinline__ void gru_compute(SMemMega& sm, const uint2* w512,
    const float* __restrict__ bi, const float* __restrict__ bh,
    float* __restrict__ hnext, int ug, int b0, int tid) {
  const int u = tid & 15, b2 = (tid >> 4) & 3, ks = tid >> 6;
  const int uG = (ug << 4) + u;
  float ar = 0.f, az = 0.f, ani = 0.f, anh = 0.f;
  const uint2* w = w512 + (size_t)(ks * RPK) * 512 + uG;
#pragma unroll 8
  for (int j = 0; j < RPK; j++) {
    uint2 wv = w[(size_t)j * 512];
    int r = ks * RPK + j;
    float x = sm.u.gr.x[b2][r];
    float2 f0 = cvt2(wv.x);
    float2 f1 = cvt2(wv.y);
    ar = fmaf(x, f0.x, ar);
    az = fmaf(x, f0.y, az);
    float t = x * f1.x;
    if (r < DXI) ani += t; else anh += t;
  }
  sm.u.gr.part4[ks][(u << 2) + b2] = make_float4(ar, az, ani, anh);
  __syncthreads();
  if (tid < 64) {
    int uu = tid >> 2, bb2 = tid & 3;
    float4 s = make_float4(0.f, 0.f, 0.f, 0.f);
#pragma unroll
    for (int l = 0; l < 16; l++) {
      float4 v = sm.u.gr.part4[l][(uu << 2) + bb2];
      s.x += v.x; s.y += v.y; s.z += v.z; s.w += v.w;
    }
    int uGf = (ug << 4) + uu;
    float r = fast_sigmoid(s.x + bi[uGf] + bh[uGf]);
    float z = fast_sigmoid(s.y + bi[512 + uGf] + bh[512 + uGf]);
    float n = fast_tanh(s.z + bi[1024 + uGf] + r * (s.w + bh[1024 + uGf]));
    float hv = sm.u.gr.x[bb2][DXI + uGf];
    sta(&hnext[((size_t)(b0 + bb2) << 9) + uGf], (1.f - z) * n + z * hv);
  }
}

__global__ __launch_bounds__(NTHR) void mega(Params p) {
  __shared__ SMemMega sm;
  const int blk = blockIdx.x, tid = threadIdx.x;
  const int ug = blk & 31, bg = blk >> 5, b0 = bg * 4;   // P1/P3 identity
  const int bS = blk & 31, t8 = blk >> 5, t0g = t8 << 6; // P2 identity
  unsigned epoch = 0;
  unsigned* flags = p.barc;
  unsigned* gen = p.barc + 384;

  // one-time: keys tile -> LDS, zero ctxL
  {
    const uint4* src = (const uint4*)(p.hkeys + (((size_t)(bS << 9) + t0g) << 9));
    uint4* dst = (uint4*)sm.keysL;
    for (int i = tid; i < 4096; i += NTHR) dst[i] = src[i];
    for (int i = tid; i < 2048; i += NTHR) sm.ctxL[i >> 9][i & 511] = 0.f;
  }
  __syncthreads();

#pragma clang loop unroll(disable)
  for (int step = 0; step <= 400; step++) {
    const int par = step & 1;
    float* hA_prev = p.hA + par * 16384;
    float* hA_next = p.hA + (par ^ 1) * 16384;
    float* hO_prev = p.hO + par * 16384;
    float* hO_next = p.hO + (par ^ 1) * 16384;

    // ======== P1: (ug<4) mel/gate of step-1 + prenet->decin ; all: GRU1 ========
    if (ug == 0) {
      for (int i = tid; i < 2048; i += NTHR)
        sta(&p.ctxacc[(b0 << 9) + i], 0.f);
    }
    if (ug < 4) {
      const int bb = b0 + ug;
      sm.u.s6.xh[tid] = (tid < 512) ? lda(&hO_prev[(bb << 9) + tid])
                                    : sm.ctxL[ug][tid - 512];
      __syncthreads();
      const int prev = step - 1;
      bool masked = prev > p.mel_lens[bb];
      {
        int m = tid & 127, ks = tid >> 7;
        const HU4* dp = (const HU4*)(p.decT + (size_t)m * 1024 + ks * 128);
        float a = 0.f;
#pragma unroll 4
        for (int it = 0; it < 16; it++) {
          HU4 raw = dp[it];
          int kb = ks * 128 + it * 8;
#pragma unroll
          for (int h2 = 0; h2 < 4; h2++) {
            float2 w = __half22float2(raw.h[h2]);
            a = fmaf(sm.u.s6.xh[kb + h2 * 2], w.x, a);
            a = fmaf(sm.u.s6.xh[kb + h2 * 2 + 1], w.y, a);
          }
        }
        sm.u.s6.red[tid] = a;
      }
      __syncthreads();
      if (tid < 128) {
        float mv = p.dec_b[tid];
#pragma unroll
        for (int j = 0; j < 8; j++) mv += sm.u.s6.red[tid + j * 128];
        sm.u.s6.mel[tid] = mv;
        if (step >= 1)
          p.out_mel[(size_t)bb * 51200 + (size_t)prev * 128 + tid] = masked ? 0.f : mv;
      }
      __syncthreads();
      sm.u.s6.red[tid] = sm.u.s6.xh[tid] * __half2float(p.gateh[tid]);
      __syncthreads();
      if (tid < 64) {
        float g = 0.f;
#pragma unroll
        for (int j = 0; j < 16; j++) g += sm.u.s6.red[tid + j * 64];
#pragma unroll
        for (int off = 32; off > 0; off >>= 1) g += __shfl_xor(g, off, 64);
        if (tid == 0 && step >= 1)
          p.out_gate[bb * 400 + prev] = masked ? 1000.f : (g + p.gate_b[0]);
      }
      __syncthreads();
      if (step < 400) {
        {
          int pc = tid & 255, ks = tid >> 8;
          const HU4* wp = (const HU4*)(p.pre1T + (size_t)pc * 128 + ks * 32);
          float a = 0.f;
#pragma unroll
          for (int it = 0; it < 4; it++) {
            HU4 raw = wp[it];
            int kb = ks * 32 + it * 8;
#pragma unroll
            for (int h2 = 0; h2 < 4; h2++) {
              float2 w = __half22float2(raw.h[h2]);
              a = fmaf(sm.u.s6.mel[kb + h2 * 2], w.x, a);
              a = fmaf(sm.u.s6.mel[kb + h2 * 2 + 1], w.y, a);
            }
          }
          sm.u.s6.red[tid] = a;
        }
        __syncthreads();
        if (tid < 256) {
          float a = sm.u.s6.red[tid] + sm.u.s6.red[tid + 256] +
                    sm.u.s6.red[tid + 512] + sm.u.s6.red[tid + 768];
          sm.u.s6.p1[tid] = fmaxf(a, 0.f);
        }
        __syncthreads();
        {
          int pc = tid & 255, ks = tid >> 8;
          const HU4* wp = (const HU4*)(p.pre2T + (size_t)pc * 256 + ks * 64);
          float a = 0.f;
#pragma unroll
          for (int it = 0; it < 8; it++) {
            HU4 raw = wp[it];
            int kb = ks * 64 + it * 8;
#pragma unroll
            for (int h2 = 0; h2 < 4; h2++) {
              float2 w = __half22float2(raw.h[h2]);
              a = fmaf(sm.u.s6.p1[kb + h2 * 2], w.x, a);
              a = fmaf(sm.u.s6.p1[kb + h2 * 2 + 1], w.y, a);
            }
          }
          sm.u.s6.red[tid] = a;
        }
        __syncthreads();
        if (tid < 256) {
          float a = sm.u.s6.red[tid] + sm.u.s6.red[tid + 256] +
                    sm.u.s6.red[tid + 512] + sm.u.s6.red[tid + 768];
          sta(&p.decin[(bb << 8) + tid], (step == 0) ? 0.f : fmaxf(a, 0.f));
        }
        __syncthreads();
        set_flagD: ;
        if (tid == 0) {
          asm volatile("s_waitcnt vmcnt(0) lgkmcnt(0)" ::: "memory");
          __hip_atomic_store(&p.flagsD[(bg << 2) + ug], step + 1, __ATOMIC_RELAXED,
                             __HIP_MEMORY_SCOPE_AGENT);
        }
      }
    }
    if (step == 400) return;
    __syncthreads();
    // all blocks: stage ctx + hA into x
    for (int i = tid; i < 2048; i += NTHR) {
      int b2 = i >> 9, a = i & 511;
      sm.u.gr.x[b2][256 + a] = sm.ctxL[b2][a];
    }
    for (int i = tid; i < 2048; i += NTHR) {
      int b2 = i >> 9, a = i & 511;
      sm.u.gr.x[b2][768 + a] = lda(&hA_prev[((size_t)(b0 + b2) << 9) + a]);
    }
    // wait for the 4 decin producers of this group
    if (tid < 64) {
      while (true) {
        int v = (tid < 4) ? ldai(&p.flagsD[(bg << 2) + tid]) : 0x7fffffff;
        if (__all(v >= step + 1)) break;
        __builtin_amdgcn_s_sleep(1);
      }
    }
    __syncthreads();
    for (int i = tid; i < 1024; i += NTHR) {
      int b2 = i >> 8, r = i & 255;
      sm.u.gr.x[b2][r] = lda(&p.decin[((b0 + b2) << 8) + r]);
    }
    __syncthreads();
    gru_compute<768, 80>(sm, (const uint2*)p.gw1T, p.attn_bi, p.attn_bh,
                         hA_next, ug, b0, tid);
    __syncthreads();
    if (tid == 0) {
      asm volatile("s_waitcnt vmcnt(0) lgkmcnt(0)" ::: "memory");
      __hip_atomic_store(&p.flagsA[blk], step + 1, __ATOMIC_RELAXED,
                         __HIP_MEMORY_SCOPE_AGENT);
    }

    // ======== P2: conv + q + score + e + ctx-partial atomics ========
    if (tid < 64) {
      const int* f = p.flagsA + ((bS >> 2) << 5);
      while (true) {
        int v = (tid < 32) ? ldai(&f[tid]) : 0x7fffffff;
        if (__all(v >= step + 1)) break;
        __builtin_amdgcn_s_sleep(1);
      }
    }
    __syncthreads();
    {
      const int tlen = p.text_lens[bS];
      for (int j = tid; j < 94; j += NTHR) {
        int pp = t0g - 15 + j;
        bool ok = (unsigned)pp < 512u;
        sm.u.s3.aw[j] = ok ? lda(&p.attw[(bS << 9) + pp]) : 0.f;
        sm.u.s3.ac[j] = ok ? lda(&p.attcum[(bS << 9) + pp]) : 0.f;
      }
      if (tid < 512) sm.u.s3.hA_s[tid] = lda(&hA_next[(bS << 9) + tid]);
      __syncthreads();
      for (int i = tid; i < 2048; i += NTHR) {
        int tt = i >> 5, f = i & 31;
        const float* w0 = p.conv_w + f * 62;
        float a = 0.f;
#pragma unroll
        for (int k = 0; k < 31; k++)
          a = fmaf(w0[k], sm.u.s3.aw[tt + k], fmaf(w0[31 + k], sm.u.s3.ac[tt + k], a));
        sm.u.s3.locS[tt][f] = a;
      }
      {
        int a = tid & 511, ks = tid >> 9;
        const HU4* qp = (const HU4*)(p.qwT + (size_t)a * 512 + ks * 256);
        float q0 = 0.f, q1 = 0.f;
#pragma unroll 4
        for (int it = 0; it < 32; it++) {
          HU4 raw = qp[it];
          int kb = ks * 256 + it * 8;
#pragma unroll
          for (int h2 = 0; h2 < 4; h2++) {
            float2 w = __half22float2(raw.h[h2]);
            q0 = fmaf(sm.u.s3.hA_s[kb + h2 * 2], w.x, q0);
            q1 = fmaf(sm.u.s3.hA_s[kb + h2 * 2 + 1], w.y, q1);
          }
        }
        sm.u.s3.qpart[ks][a] = q0 + q1;
      }
      __syncthreads();
      if (tid < 512)
        sm.u.s3.qS[tid] = sm.u.s3.qpart[0][tid] + sm.u.s3.qpart[1][tid] + p.loc_b[tid];
      __syncthreads();
      const int lane = tid & 63, wv = tid >> 6;
      float acc[4][8];
      float4 qA = *(const float4*)&sm.u.s3.qS[lane * 8];
      float4 qB = *(const float4*)&sm.u.s3.qS[lane * 8 + 4];
#pragma unroll
      for (int j = 0; j < 4; j++) {
        int tL = wv * 4 + j;
        HU4 raw; raw.u = *(const uint4*)&sm.keysL[tL * 512 + lane * 8];
        float2 k0 = __half22float2(raw.h[0]), k1 = __half22float2(raw.h[1]);
        float2 k2 = __half22float2(raw.h[2]), k3 = __half22float2(raw.h[3]);
        acc[j][0] = qA.x + k0.x; acc[j][1] = qA.y + k0.y;
        acc[j][2] = qA.z + k1.x; acc[j][3] = qA.w + k1.y;
        acc[j][4] = qB.x + k2.x; acc[j][5] = qB.y + k2.y;
        acc[j][6] = qB.z + k3.x; acc[j][7] = qB.w + k3.y;
      }
#pragma unroll 4
      for (int f = 0; f < 32; f++) {
        HU4 rw; rw.u = *(const uint4*)(p.locwh + (size_t)f * 512 + lane * 8);
        float2 w0 = __half22float2(rw.h[0]), w1 = __half22float2(rw.h[1]);
        float2 w2 = __half22float2(rw.h[2]), w3 = __half22float2(rw.h[3]);
#pragma unroll
        for (int j = 0; j < 4; j++) {
          float lf = sm.u.s3.locS[wv * 4 + j][f];
          acc[j][0] = fmaf(lf, w0.x, acc[j][0]); acc[j][1] = fmaf(lf, w0.y, acc[j][1]);
          acc[j][2] = fmaf(lf, w1.x, acc[j][2]); acc[j][3] = fmaf(lf, w1.y, acc[j][3]);
          acc[j][4] = fmaf(lf, w2.x, acc[j][4]); acc[j][5] = fmaf(lf, w2.y, acc[j][5]);
          acc[j][6] = fmaf(lf, w3.x, acc[j][6]); acc[j][7] = fmaf(lf, w3.y, acc[j][7]);
        }
      }
      float4 sA = *(const float4*)(p.score_w + lane * 8);
      float4 sB = *(const float4*)(p.score_w + lane * 8 + 4);
      float sbias = p.score_b[0];
      float e_reg[4];
#pragma unroll
      for (int j = 0; j < 4; j++) {
        float pv = fast_tanh(acc[j][0]) * sA.x + fast_tanh(acc[j][1]) * sA.y +
                   fast_tanh(acc[j][2]) * sA.z + fast_tanh(acc[j][3]) * sA.w +
                   fast_tanh(acc[j][4]) * sB.x + fast_tanh(acc[j][5]) * sB.y +
                   fast_tanh(acc[j][6]) * sB.z + fast_tanh(acc[j][7]) * sB.w;
#pragma unroll
        for (int off = 32; off > 0; off >>= 1) pv += __shfl_xor(pv, off, 64);
        int t = t0g + wv * 4 + j;
        e_reg[j] = (t > tlen) ? 0.f : __expf(pv + sbias);
      }
      if (lane == 0) {
#pragma unroll
        for (int j = 0; j < 4; j++) sm.u.s3.eS[wv * 4 + j] = e_reg[j];
      }
      float cp[8] = {0.f, 0.f, 0.f, 0.f, 0.f, 0.f, 0.f, 0.f};
#pragma unroll
      for (int j = 0; j < 4; j++) {
        int tL = wv * 4 + j;
        HU4 raw; raw.u = *(const uint4*)&sm.keysL[tL * 512 + lane * 8];
        float2 k0 = __half22float2(raw.h[0]), k1 = __half22float2(raw.h[1]);
        float2 k2 = __half22float2(raw.h[2]), k3 = __half22float2(raw.h[3]);
        float e = e_reg[j];
        cp[0] = fmaf(e, k0.x, cp[0]); cp[1] = fmaf(e, k0.y, cp[1]);
        cp[2] = fmaf(e, k1.x, cp[2]); cp[3] = fmaf(e, k1.y, cp[3]);
        cp[4] = fmaf(e, k2.x, cp[4]); cp[5] = fmaf(e, k2.y, cp[5]);
        cp[6] = fmaf(e, k3.x, cp[6]); cp[7] = fmaf(e, k3.y, cp[7]);
      }
      __syncthreads();
      if (wv < 8) {
        float4* r0 = (float4*)&sm.u.s3.cpred[wv][lane * 8];
        r0[0] = make_float4(cp[0], cp[1], cp[2], cp[3]);
        r0[1] = make_float4(cp[4], cp[5], cp[6], cp[7]);
      }
      __syncthreads();
      if (wv >= 8) {
        float* r0 = &sm.u.s3.cpred[wv - 8][lane * 8];
#pragma unroll
        for (int i = 0; i < 8; i++) r0[i] += cp[i];
      }
      __syncthreads();
      if (tid < 512) {
        float s = 0.f;
#pragma unroll
        for (int j = 0; j < 8; j++) s += sm.u.s3.cpred[j][tid];
        atomicAdd(&p.ctxacc[(bS << 9) + tid], s);
      }
      if (tid < 64) {
        float e = sm.u.s3.eS[tid];
        sta(&p.ebuf[(bS << 9) + t0g + tid], e);
        float z = e;
#pragma unroll
        for (int off = 32; off > 0; off >>= 1) z += __shfl_xor(z, off, 64);
        if (tid == 0) sta(&p.zpart[bS * 8 + t8], z);
      }
    }
    gbar(flags, gen, ++epoch, blk, tid);

    // ======== P3: ctx normalize + GRU2 ========
    {
      if (tid < 4) {
        float Z = 0.f;
#pragma unroll
        for (int j = 0; j < 8; j++) Z += lda(&p.zpart[(b0 + tid) * 8 + j]);
        sm.invZ[tid] = fast_rcp(Z);
      }
      __syncthreads();
      for (int i = tid; i < 2048; i += NTHR) {
        int b2 = i >> 9, a = i & 511;
        sm.ctxL[b2][a] = lda(&p.ctxacc[((b0 + b2) << 9) + a]) * sm.invZ[b2];
      }
      if (ug == 0) {
        for (int i = tid; i < 2048; i += NTHR) {
          int b2 = i >> 9, t = i & 511;
          int bb = b0 + b2;
          float v = lda(&p.ebuf[(bb << 9) + t]) * sm.invZ[b2];
          sta(&p.attw[(bb << 9) + t], v);
          float oc = lda(&p.attcum[(bb << 9) + t]);
          sta(&p.attcum[(bb << 9) + t], oc + v);
          p.out_attn[(size_t)bb * 204800 + (size_t)step * 512 + t] = v;
        }
      }
      __syncthreads();
      for (int i = tid; i < 2048; i += NTHR) {
        int b2 = i >> 9, a = i & 511;
        sm.u.gr.x[b2][a] = lda(&hA_next[((size_t)(b0 + b2) << 9) + a]);
      }
      for (int i = tid; i < 2048; i += NTHR) {
        int b2 = i >> 9, a = i & 511;
        sm.u.gr.x[b2][512 + a] = sm.ctxL[b2][a];
      }
      for (int i = tid; i < 2048; i += NTHR) {
        int b2 = i >> 9, a = i & 511;
        sm.u.gr.x[b2][1024 + a] = lda(&hO_prev[((size_t)(b0 + b2) << 9) + a]);
      }
      __syncthreads();
      gru_compute<1024, 96>(sm, (const uint2*)p.gw2T, p.out_bi, p.out_bh,
                            hO_next, ug, b0, tid);
    }
    gbar(flags, gen, ++epoch, blk, tid);
  }
}

extern "C" void kernel_launch(void* const* d_in, const int* in_sizes, int n_in,
                              void* d_out, int out_size, void* d_ws, size_t ws_size,
                              hipStream_t stream) {
  Params p;
  p.enc       = (const float*)d_in[0];
  p.text_lens = (const int*)d_in[2];
  p.mel_lens  = (const int*)d_in[3];
  p.pre_w1    = (const float*)d_in[5];
  p.pre_w2    = (const float*)d_in[6];
  p.attn_wi   = (const float*)d_in[7];
  p.attn_wh   = (const float*)d_in[8];
  p.attn_bi   = (const float*)d_in[9];
  p.attn_bh   = (const float*)d_in[10];
  p.q_w       = (const float*)d_in[11];
  p.k_w       = (const float*)d_in[12];
  p.score_w   = (const float*)d_in[13];
  p.score_b   = (const float*)d_in[14];
  p.conv_w    = (const float*)d_in[15];
  p.loc_w     = (const float*)d_in[16];
  p.loc_b     = (const float*)d_in[17];
  p.out_wi    = (const float*)d_in[18];
  p.out_wh    = (const float*)d_in[19];
  p.out_bi    = (const float*)d_in[20];
  p.out_bh    = (const float*)d_in[21];
  p.dec_w     = (const float*)d_in[22];
  p.dec_b     = (const float*)d_in[23];
  p.gate_w    = (const float*)d_in[24];
  p.gate_b    = (const float*)d_in[25];

  float* ws = (float*)d_ws;
  p.hkeys  = (__half*)(ws);                    // 8,388,608 halfs
  p.gw1T   = (__half*)(ws + 4194304);          // 2,621,440 halfs
  p.gw2T   = (__half*)(ws + 5505024);          // 3,145,728 halfs
  p.decT   = (__half*)(ws + 7077888);          // 131,072 halfs
  p.pre1T  = (__half*)(ws + 7143424);          // 32,768
  p.pre2T  = (__half*)(ws + 7159808);          // 65,536
  p.gateh  = (__half*)(ws + 7192576);          // 1,024
  p.locwh  = (__half*)(ws + 7193088);          // 16,384
  p.qwT    = (__half*)(ws + 7201280);          // 262,144
  p.hA     = ws + 7332352;                     // 2 x 16384
  p.hO     = ws + 7365120;                     // 2 x 16384
  p.attw   = ws + 7397888;                     // 16384
  p.attcum = ws + 7414272;                     // 16384
  p.decin  = ws + 7430656;                     // 8192
  p.stateZ = p.hA;                             // zero region: hA,hO,attw,attcum,decin = 106,496
  p.ebuf   = ws + 7438848;                     // 16384
  p.zpart  = ws + 7455232;                     // 256
  p.ctxacc = ws + 7455488;                     // 16384
  p.flagsA = (int*)(ws + 7471872);             // 256 ints
  p.flagsD = p.flagsA + 256;                   // 32 ints
  p.barc   = (unsigned*)(ws + 7472160);        // 512 uints (flags @0, gen @384)
  float* out = (float*)d_out;
  p.out_mel  = out;
  p.out_gate = out + 1638400;
  p.out_attn = out + 1651200;
  p.out_mask = out + 8204800;

  k_repack<<<2048, 256, 0, stream>>>(p);
  k_keys<<<dim3(128, 8), 512, 0, stream>>>(p);
  void* args[] = { (void*)&p };
  hipLaunchCooperativeKernel((const void*)mega, dim3(NBLK), dim3(NTHR), args, 0, stream);
}